// Round 2
// baseline (410.757 us; speedup 1.0000x reference)
//
#include <hip/hip_runtime.h>

// Correlation cost volume, MAX_DISP=4 (81 displacements).
// out[b,(dy+4)*9+(dx+4),y,x] = (1/C) * sum_c first[b,c,y,x]*second[b,c,y+dy,x+dx]
//
// R2: ONE dy per block (acc = 9 float4 = 36 VGPRs -- R1 spilled 108-float acc
// to scratch: VGPR_Count=92 < 108 acc floats, VALUBusy 8.7%, dur 220us).
// Grid 3x16x36 = 1728 blocks of 128 thr -> 13.5 waves/CU (3x R1 occupancy).
// 2 channels staged per barrier, double-buffered LDS, depth-1 pair prefetch.

#define B_    4
#define C_    128
#define H_    128
#define W_    192
#define HW_   (H_ * W_)
#define CHW_  (C_ * HW_)

#define TX    64    // tile width (pixels)
#define TY    8     // tile height
#define SCOLS 72    // TX + 8 halo
#define SFLOATS (TY * SCOLS)      // 576 floats per channel tile
#define NCHUNK  (SFLOATS / 4)     // 144 float4 chunks

__global__ __launch_bounds__(128, 3)
void corr_kernel(const float* __restrict__ first,
                 const float* __restrict__ second,
                 float* __restrict__ out)
{
    // [pair-buffer][channel-within-pair][tile]
    __shared__ float sS[2][2][SFLOATS];

    const int t  = threadIdx.x;
    const int tx = t & 15;       // 0..15 (4 px each)
    const int ty = t >> 4;       // 0..7
    const int x0 = blockIdx.x * TX;
    const int y0 = blockIdx.y * TY;
    const int bz = blockIdx.z;   // b*9 + (dy+4)
    const int b  = bz / 9;
    const int dyi = bz - 9 * b;  // 0..8
    const int dy  = dyi - 4;

    const int X = x0 + 4 * tx;   // this thread's first output x
    const int y = y0 + ty;

    const float* fptr = first + (size_t)b * CHW_ + (size_t)y * W_ + X;

    // --- staging chunk assignment (second tile: TY rows x SCOLS, zero-padded)
    // chunk k covers LDS floats [4k,4k+4): row = k/18, col4 = k%18.
    // LDS row r <-> output row y0+r, sourced from second row y0+r+dy.
    const int k0 = t;                       // chunks 0..127: all threads
    const int r0 = k0 / 18, cc0 = k0 % 18;
    const int grow0 = y0 + dy + r0;
    const int gcol0 = x0 - 4 + 4 * cc0;
    const bool v0 = (grow0 >= 0) && (grow0 < H_) && (gcol0 >= 0) && (gcol0 <= W_ - 4);
    const float* sptr0 = second + (size_t)b * CHW_ + (size_t)grow0 * W_ + gcol0;

    const int k1 = 128 + t;                 // chunks 128..143: threads 0..15
    const bool act1 = (k1 < NCHUNK);        // t < 16
    const int r1 = k1 / 18, cc1 = k1 % 18;
    const int grow1 = y0 + dy + r1;
    const int gcol1 = x0 - 4 + 4 * cc1;
    const bool v1 = act1 && (grow1 >= 0) && (grow1 < H_) && (gcol1 >= 0) && (gcol1 <= W_ - 4);
    const float* sptr1 = second + (size_t)b * CHW_ + (size_t)grow1 * W_ + gcol1;

    const float4 z4 = make_float4(0.f, 0.f, 0.f, 0.f);

    // staging registers: [pipeline slot][channel within pair]
    float4 Sa[2][2], Sb[2][2], F[2][2];

    auto loadPair = [&](int slot, int c) {   // c = first channel of the pair
        #pragma unroll
        for (int u = 0; u < 2; ++u) {
            const size_t co = (size_t)(c + u) * HW_;
            Sa[slot][u] = v0 ? *(const float4*)(sptr0 + co) : z4;
            if (act1) Sb[slot][u] = v1 ? *(const float4*)(sptr1 + co) : z4;
            F[slot][u] = *(const float4*)(fptr + co);
        }
    };
    auto writePair = [&](int slot) {
        #pragma unroll
        for (int u = 0; u < 2; ++u) {
            *(float4*)&sS[slot][u][4 * t] = Sa[slot][u];
            if (act1) *(float4*)&sS[slot][u][512 + 4 * t] = Sb[slot][u];
        }
    };

    // prologue: pair0 -> LDS[0]; pair1 staged in regs slot 1
    loadPair(0, 0);
    writePair(0);
    loadPair(1, 2);

    float4 acc[9];
    #pragma unroll
    for (int i = 0; i < 9; ++i) acc[i] = z4;

    #pragma unroll 2
    for (int p = 0; p < 64; ++p) {           // pair p = channels 2p, 2p+1
        const int pb = p & 1;
        __syncthreads();                     // LDS[pb] (pair p) ready
        if (p + 1 < 64) writePair(pb ^ 1);   // stage pair p+1 (loads issued last iter)
        const float4 f0 = F[pb][0];
        const float4 f1 = F[pb][1];
        if (p + 2 < 64) loadPair(pb, 2 * (p + 2));   // prefetch pair p+2

        #pragma unroll
        for (int u = 0; u < 2; ++u) {
            const float* srow = &sS[pb][u][ty * SCOLS + 4 * tx];
            float w[12];
            *(float4*)(w + 0) = *(const float4*)(srow);
            *(float4*)(w + 4) = *(const float4*)(srow + 4);
            *(float4*)(w + 8) = *(const float4*)(srow + 8);
            const float4 fc = u ? f1 : f0;
            #pragma unroll
            for (int dxi = 0; dxi < 9; ++dxi) {
                float4& a = acc[dxi];
                a.x += fc.x * w[dxi + 0];
                a.y += fc.y * w[dxi + 1];
                a.z += fc.z * w[dxi + 2];
                a.w += fc.w * w[dxi + 3];
            }
        }
    }

    // epilogue: out[b, dyi*9 + dxi, y, X..X+3]
    const float scale = 1.0f / (float)C_;
    #pragma unroll
    for (int dxi = 0; dxi < 9; ++dxi) {
        const int d = dyi * 9 + dxi;
        float4 r = acc[dxi];
        r.x *= scale; r.y *= scale; r.z *= scale; r.w *= scale;
        *(float4*)(out + ((size_t)b * 81 + d) * HW_ + (size_t)y * W_ + X) = r;
    }
}

extern "C" void kernel_launch(void* const* d_in, const int* in_sizes, int n_in,
                              void* d_out, int out_size, void* d_ws, size_t ws_size,
                              hipStream_t stream) {
    const float* first  = (const float*)d_in[0];
    const float* second = (const float*)d_in[1];
    float* out = (float*)d_out;

    dim3 grid(W_ / TX, H_ / TY, B_ * 9);   // 3 x 16 x 36 = 1728 blocks
    dim3 block(128);
    corr_kernel<<<grid, block, 0, stream>>>(first, second, out);
}

// Round 4
// 230.077 us; speedup vs baseline: 1.7853x; 1.7853x over previous
//
#include <hip/hip_runtime.h>

// Correlation cost volume, MAX_DISP=4 (81 displacements).
// out[b,(dy+4)*9+(dx+4),y,x] = (1/C) * sum_c first[b,c,y,x]*second[b,c,y+dy,x+dx]
//
// R4: classic VGPR->ds_write staging (R3's global_load_lds DMA is broken under
// exec-masked lanes: base = first ACTIVE lane -> shifted tile, absmax 1.6e8).
// R1/R2's 220-320us came from scratch spill of lambda-captured runtime-indexed
// staging arrays (R2: WRITE_SIZE 506MB vs 32MB output). This version is
// straight-line: named float4 vars only; acc[9]/w[12] only constant-indexed
// after full unroll. One dy per block, acc = 9 float4. Double-buffered LDS,
// depth-2 prefetch for both inputs. Grid 3x16x36 = 1728 blocks x 128 thr.

#define B_    4
#define C_    128
#define H_    128
#define W_    192
#define HW_   (H_ * W_)
#define CHW_  (C_ * HW_)

#define TX    64    // tile width (pixels)
#define TY    8     // tile height
#define SCOLS 72    // TX + 8 halo
#define SFLOATS (TY * SCOLS)      // 576 floats per channel tile
#define NCHUNK  (SFLOATS / 4)     // 144 float4 chunks

__global__ __launch_bounds__(128, 3)
void corr_kernel(const float* __restrict__ first,
                 const float* __restrict__ second,
                 float* __restrict__ out)
{
    __shared__ float sS[2][SFLOATS];   // double-buffered second tile

    const int t  = threadIdx.x;
    const int tx = t & 15;       // 0..15 (4 px each)
    const int ty = t >> 4;       // 0..7
    const int x0 = blockIdx.x * TX;
    const int y0 = blockIdx.y * TY;
    const int bz = blockIdx.z;   // b*9 + (dy+4)
    const int b  = bz / 9;
    const int dyi = bz - 9 * b;  // 0..8
    const int dy  = dyi - 4;

    const int X = x0 + 4 * tx;   // this thread's first output x
    const int y = y0 + ty;

    const float* fptr = first + (size_t)b * CHW_ + (size_t)y * W_ + X;

    // --- staging chunk assignment (second tile: TY rows x SCOLS cols) ---
    // chunk k covers LDS floats [4k,4k+4): row = k/18, col4 = k%18.
    // LDS row r <-> output row y0+r, sourced from second row y0+r+dy.
    // Validity is all-or-nothing per 16B chunk (halo=4 floats, W%4==0).
    const int r0 = t / 18, cc0 = t % 18;            // chunk t (all threads)
    const int grow0 = y0 + dy + r0;
    const int gcol0 = x0 - 4 + 4 * cc0;
    const bool v0 = (grow0 >= 0) && (grow0 < H_) && (gcol0 >= 0) && (gcol0 <= W_ - 4);
    const float* sptr0 = second + (size_t)b * CHW_ + (size_t)grow0 * W_ + gcol0;

    const int k1 = 128 + t;                          // chunk 128+t (t<16)
    const bool act1 = (k1 < NCHUNK);
    const int r1 = k1 / 18, cc1 = k1 % 18;
    const int grow1 = y0 + dy + r1;
    const int gcol1 = x0 - 4 + 4 * cc1;
    const bool v1 = act1 && (grow1 >= 0) && (grow1 < H_) && (gcol1 >= 0) && (gcol1 <= W_ - 4);
    const float* sptr1 = second + (size_t)b * CHW_ + (size_t)grow1 * W_ + gcol1;

    const float4 z4 = make_float4(0.f, 0.f, 0.f, 0.f);

    // ---- prologue: stage c=0 into LDS[0]; prefetch c=1 into regs ----
    float4 Sa = v0 ? *(const float4*)(sptr0) : z4;
    float4 Sb = v1 ? *(const float4*)(sptr1) : z4;
    *(float4*)&sS[0][4 * t] = Sa;
    if (act1) *(float4*)&sS[0][512 + 4 * t] = Sb;
    Sa = v0 ? *(const float4*)(sptr0 + HW_) : z4;
    Sb = v1 ? *(const float4*)(sptr1 + HW_) : z4;
    float4 Fc = *(const float4*)(fptr);
    float4 Fn = *(const float4*)(fptr + HW_);

    float4 acc[9];
    #pragma unroll
    for (int i = 0; i < 9; ++i) acc[i] = z4;

    #pragma unroll 2
    for (int c = 0; c < C_; ++c) {
        const int pb = c & 1;
        __syncthreads();                 // LDS[pb] ready; LDS[pb^1] free
        if (c + 1 < C_) {                // stage c+1 (Sa/Sb hold c+1 data)
            *(float4*)&sS[pb ^ 1][4 * t] = Sa;
            if (act1) *(float4*)&sS[pb ^ 1][512 + 4 * t] = Sb;
        }
        if (c + 2 < C_) {                // prefetch c+2
            const size_t co = (size_t)(c + 2) * HW_;
            Sa = v0 ? *(const float4*)(sptr0 + co) : z4;
            Sb = v1 ? *(const float4*)(sptr1 + co) : z4;
        }

        // 12-float window -> 9 sliding dot-product taps, 4 px per thread
        const float* srow = &sS[pb][ty * SCOLS + 4 * tx];
        float w[12];
        *(float4*)(w + 0) = *(const float4*)(srow);
        *(float4*)(w + 4) = *(const float4*)(srow + 4);
        *(float4*)(w + 8) = *(const float4*)(srow + 8);
        #pragma unroll
        for (int dxi = 0; dxi < 9; ++dxi) {
            acc[dxi].x += Fc.x * w[dxi + 0];
            acc[dxi].y += Fc.y * w[dxi + 1];
            acc[dxi].z += Fc.z * w[dxi + 2];
            acc[dxi].w += Fc.w * w[dxi + 3];
        }

        Fc = Fn;
        if (c + 2 < C_) Fn = *(const float4*)(fptr + (size_t)(c + 2) * HW_);
    }

    // epilogue: out[b, dyi*9 + dxi, y, X..X+3]
    const float scale = 1.0f / (float)C_;
    #pragma unroll
    for (int dxi = 0; dxi < 9; ++dxi) {
        const int d = dyi * 9 + dxi;
        float4 r = acc[dxi];
        r.x *= scale; r.y *= scale; r.z *= scale; r.w *= scale;
        *(float4*)(out + ((size_t)b * 81 + d) * HW_ + (size_t)y * W_ + X) = r;
    }
}

extern "C" void kernel_launch(void* const* d_in, const int* in_sizes, int n_in,
                              void* d_out, int out_size, void* d_ws, size_t ws_size,
                              hipStream_t stream) {
    const float* first  = (const float*)d_in[0];
    const float* second = (const float*)d_in[1];
    float* out = (float*)d_out;

    dim3 grid(W_ / TX, H_ / TY, B_ * 9);   // 3 x 16 x 36 = 1728 blocks
    dim3 block(128);
    corr_kernel<<<grid, block, 0, stream>>>(first, second, out);
}